// Round 5
// baseline (3815.147 us; speedup 1.0000x reference)
//
#include <hip/hip_runtime.h>

// ---------------------------------------------------------------------------
// AlternatingHGN: RELS={(0,1),(1,2),(0,2)}, NE=100000 each, NNZ=500000,
// C_IN=16, EMB=WIDTH=64, OUT=16.
//
// Design (ws-lean, 158.4 MB):
//  - counts/inv-counts per role computed once (indices reused every layer)
//  - pool = scatter-matmul: per nnz, (v * 1/cnt) @ pw scattered straight into
//    per-entity pre-activation acc (fp32 atomics). No per-role sum tables.
//  - relu + BN stats in place on acc; BN folded into the bcast weight
//    (w'' = bw/sigma, bias = -mu@w'') when building gather tables embW (bf16)
//  - final pool scatters straight into d_out
// ---------------------------------------------------------------------------

#define NE_  100000
#define NNZ_ 500000

__device__ __forceinline__ ushort f2bf(float x) {
    uint32_t u = __float_as_uint(x);
    u += 0x7fffu + ((u >> 16) & 1u);
    return (ushort)(u >> 16);
}
__device__ __forceinline__ float bf2f(ushort h) {
    return __uint_as_float(((uint32_t)h) << 16);
}

// ------------------------------ kernels ------------------------------------

__global__ __launch_bounds__(256)
void count_kernel(const int* __restrict__ row, const int* __restrict__ col,
                  int* __restrict__ cntR, int* __restrict__ cntC)
{
    int g = blockIdx.x * 256 + threadIdx.x;
    if (g < NNZ_) {
        atomicAdd(&cntR[row[g]], 1);
        atomicAdd(&cntC[col[g]], 1);
    }
}

__global__ __launch_bounds__(256)
void inv_kernel(const int* __restrict__ cnt, float* __restrict__ icnt, int n)
{
    int g = blockIdx.x * 256 + threadIdx.x;
    if (g < n) icnt[g] = 1.f / fmaxf((float)cnt[g], 1.f);
}

// L1 scatter-matmul: per nnz, vals(16) -> (v*icR)@pwR (16x64) into accR[row],
// (v*icC)@pwC into accC[col]. One wave per nnz.
__global__ __launch_bounds__(256)
void l1scat_kernel(const float* __restrict__ vals,
                   const int* __restrict__ row, const int* __restrict__ col,
                   const float* __restrict__ icR_t, const float* __restrict__ icC_t,
                   const float* __restrict__ pwR, const float* __restrict__ pwC,
                   float* __restrict__ accR, float* __restrict__ accC)
{
    __shared__ float2 w[16 * 64];          // 8 KB: (pwR, pwC) interleaved
    int t = threadIdx.x;
    for (int i = t; i < 1024; i += 256) w[i] = make_float2(pwR[i], pwC[i]);
    __syncthreads();
    int lane = t & 63, sub = t >> 6;
    for (int n = blockIdx.x * 4 + sub; n < NNZ_; n += gridDim.x * 4) {
        int i = row[n], j = col[n];
        float icR = icR_t[i], icC = icC_t[j];
        float vl = (lane < 16) ? vals[(size_t)n * 16 + lane] : 0.f;
        float oR = 0.f, oC = 0.f;
#pragma unroll
        for (int c = 0; c < 16; ++c) {
            float vc = __shfl(vl, c);
            float2 ww = w[c * 64 + lane];
            oR += vc * ww.x;
            oC += vc * ww.y;
        }
        atomicAdd(&accR[(size_t)i * 64 + lane], oR * icR);
        atomicAdd(&accC[(size_t)j * 64 + lane], oC * icC);
    }
}

// in-place relu + per-feature BN stats (sum, sumsq) over one entity table
__global__ __launch_bounds__(256)
void relu_stats_kernel(float* __restrict__ acc, float* __restrict__ stats)
{
    __shared__ float red[2][256];
    int t = threadIdx.x, f = t & 63, sub = t >> 6;
    float s = 0.f, s2 = 0.f;
    for (int r = blockIdx.x * 4 + sub; r < NE_; r += gridDim.x * 4) {
        float x = acc[(size_t)r * 64 + f];
        x = fmaxf(x, 0.f);
        acc[(size_t)r * 64 + f] = x;
        s += x; s2 += x * x;
    }
    red[0][t] = s; red[1][t] = s2;
    __syncthreads();
    if (sub == 0) {
        float rs = red[0][f] + red[0][64 + f] + red[0][128 + f] + red[0][192 + f];
        float rq = red[1][f] + red[1][64 + f] + red[1][128 + f] + red[1][192 + f];
        atomicAdd(&stats[f], rs);
        atomicAdd(&stats[64 + f], rq);
    }
}

// embW = bn(emb) @ bw with BN folded; bf16 output
__global__ __launch_bounds__(256)
void embw_bf16_kernel(const float* __restrict__ emb, const float* __restrict__ stats,
                      const float* __restrict__ bw, ushort* __restrict__ out)
{
    __shared__ float w[64 * 64];
    __shared__ float bias[64], invs[64], mu[64];
    __shared__ float rows[4][64];
    int t = threadIdx.x;
    if (t < 64) {
        float s = stats[t], q = stats[64 + t];
        float m = s * (1.f / (float)NE_);
        float v = q * (1.f / (float)NE_) - m * m;
        mu[t] = m;
        invs[t] = rsqrtf(v + 1e-5f);
    }
    __syncthreads();
    for (int i = t; i < 64 * 64; i += 256) w[i] = bw[i] * invs[i >> 6];
    __syncthreads();
    if (t < 64) {
        float b = 0.f;
        for (int k = 0; k < 64; ++k) b -= mu[k] * w[k * 64 + t];
        bias[t] = b;
    }
    int f = t & 63, sub = t >> 6;
    size_t base = (size_t)blockIdx.x * 32;   // 3125 blocks x 32 rows = 100000
    for (int it = 0; it < 32; it += 4) {
        __syncthreads();
        for (int i = t; i < 256; i += 256) {
            size_t rr = base + it + (i >> 6);
            rows[i >> 6][i & 63] = emb[rr * 64 + (i & 63)];
        }
        __syncthreads();
        size_t rr = base + it + sub;
        float acc = bias[f];
#pragma unroll
        for (int k = 0; k < 64; ++k) acc += rows[sub][k] * w[k * 64 + f];
        out[rr * 64 + f] = f2bf(acc);
    }
}

// L2 scatter-matmul: per nnz, v=relu(ea[row]+eb[col]) (64, bf16 gathers);
// (v*icR)@pwR (64x64) into accR[row]; (v*icC)@pwC into accC[col].
__global__ __launch_bounds__(256)
void l2scat_kernel(const ushort* __restrict__ ea, const ushort* __restrict__ eb,
                   const int* __restrict__ row, const int* __restrict__ col,
                   const float* __restrict__ icR_t, const float* __restrict__ icC_t,
                   const float* __restrict__ pwR, const float* __restrict__ pwC,
                   float* __restrict__ accR, float* __restrict__ accC)
{
    __shared__ float2 w[64 * 64];          // 32 KB
    int t = threadIdx.x;
    for (int i = t; i < 4096; i += 256) w[i] = make_float2(pwR[i], pwC[i]);
    __syncthreads();
    int lane = t & 63, sub = t >> 6;
    for (int n = blockIdx.x * 4 + sub; n < NNZ_; n += gridDim.x * 4) {
        int i = row[n], j = col[n];
        float icR = icR_t[i], icC = icC_t[j];
        float a = bf2f(ea[(size_t)i * 64 + lane]);
        float b = bf2f(eb[(size_t)j * 64 + lane]);
        float v = fmaxf(a + b, 0.f);
        float oR = 0.f, oC = 0.f;
#pragma unroll
        for (int k = 0; k < 64; ++k) {
            float vk = __shfl(v, k);
            float2 ww = w[k * 64 + lane];
            oR += vk * ww.x;
            oC += vk * ww.y;
        }
        atomicAdd(&accR[(size_t)i * 64 + lane], oR * icR);
        atomicAdd(&accC[(size_t)j * 64 + lane], oC * icC);
    }
}

// final: v=relu(ea[row]+eb[col]); (v*icR)@pw (64x16) scattered into out[row]
__global__ __launch_bounds__(256)
void fscat_kernel(const ushort* __restrict__ ea, const ushort* __restrict__ eb,
                  const int* __restrict__ row, const int* __restrict__ col,
                  const float* __restrict__ icR_t, const float* __restrict__ pw,
                  float* __restrict__ out)
{
    __shared__ float w[64 * 16];
    int t = threadIdx.x;
    for (int i = t; i < 1024; i += 256) w[i] = pw[i];
    __syncthreads();
    int lane = t & 63, sub = t >> 6;
    int o = lane & 15;
    for (int n = blockIdx.x * 4 + sub; n < NNZ_; n += gridDim.x * 4) {
        int i = row[n], j = col[n];
        float icR = icR_t[i];
        float a = bf2f(ea[(size_t)i * 64 + lane]);
        float b = bf2f(eb[(size_t)j * 64 + lane]);
        float v = fmaxf(a + b, 0.f);
        float oacc = 0.f;
#pragma unroll
        for (int k = 0; k < 64; ++k) {
            float vk = __shfl(v, k);
            oacc += vk * w[k * 16 + o];
        }
        if (lane < 16) atomicAdd(&out[(size_t)i * 16 + lane], oacc * icR);
    }
}

// ------------------------------ launch -------------------------------------

extern "C" void kernel_launch(void* const* d_in, const int* in_sizes, int n_in,
                              void* d_out, int out_size, void* d_ws, size_t ws_size,
                              hipStream_t stream)
{
    const float* vals[3] = { (const float*)d_in[0], (const float*)d_in[3], (const float*)d_in[6] };
    const int*   row[3]  = { (const int*)d_in[1], (const int*)d_in[4], (const int*)d_in[7] };
    const int*   col[3]  = { (const int*)d_in[2], (const int*)d_in[5], (const int*)d_in[8] };
    const float* pw0 = (const float*)d_in[9];
    const float* pw1 = (const float*)d_in[10];
    const float* pw2 = (const float*)d_in[11];
    const float* bw0 = (const float*)d_in[12];
    const float* bw1 = (const float*)d_in[13];
    float* out = (float*)d_out;

    // ---- workspace layout (158.4 MB total) ----
    const size_t OFF_CNT   = 0;                    // 6 * 100000 int  = 2.4 MB
    const size_t OFF_ICNT  = 2400000;              // 6 * 100000 f32  = 2.4 MB
    const size_t OFF_STATS = 4800000;              // 6 * 128 f32
    const size_t OFF_R1    = 4804096;              // 3 * 100000*64 f32 = 76.8 MB
    const size_t OFF_R2    = 81604096;             // 6 * 100000*64 bf16 = 76.8 MB
    const size_t WS_NEED   = 158404096;

    if (ws_size < WS_NEED) {
        hipMemsetAsync(d_out, 0, (size_t)out_size * 4, stream);  // clean fail
        return;
    }

    char* ws = (char*)d_ws;
    int*    cnt   = (int*)(ws + OFF_CNT);
    float*  icnt  = (float*)(ws + OFF_ICNT);
    float*  stats = (float*)(ws + OFF_STATS);
    float*  R1    = (float*)(ws + OFF_R1);
    ushort* R2    = (ushort*)(ws + OFF_R2);

    int* cnt6[6];  float* ic6[6];
    for (int k = 0; k < 6; ++k) { cnt6[k] = cnt + (size_t)k * NE_; ic6[k] = icnt + (size_t)k * NE_; }
    float* acc[3];
    for (int e = 0; e < 3; ++e) acc[e] = R1 + (size_t)e * NE_ * 64;
    ushort* tbl[6];
    for (int k = 0; k < 6; ++k) tbl[k] = R2 + (size_t)k * NE_ * 64;

    const int REL_EI[3] = { 0, 1, 0 };
    const int REL_EJ[3] = { 1, 2, 2 };

    // ---- counts (once; indices identical across layers) ----
    hipMemsetAsync(cnt, 0, 2400000, stream);
    hipMemsetAsync(stats, 0, 3072, stream);
    for (int r = 0; r < 3; ++r)
        count_kernel<<<(NNZ_ + 255) / 256, 256, 0, stream>>>(row[r], col[r],
                                                             cnt6[2 * r], cnt6[2 * r + 1]);
    inv_kernel<<<(6 * NE_ + 255) / 256, 256, 0, stream>>>(cnt, icnt, 6 * NE_);

    // ---- layer 1 pool ----
    hipMemsetAsync(R1, 0, 76800000, stream);
    for (int r = 0; r < 3; ++r)
        l1scat_kernel<<<1024, 256, 0, stream>>>(vals[r], row[r], col[r],
                                                ic6[2 * r], ic6[2 * r + 1],
                                                pw0 + (size_t)(2 * r) * 1024,
                                                pw0 + (size_t)(2 * r + 1) * 1024,
                                                acc[REL_EI[r]], acc[REL_EJ[r]]);
    for (int e = 0; e < 3; ++e)
        relu_stats_kernel<<<512, 256, 0, stream>>>(acc[e], stats + e * 128);

    // ---- bcast tables embW1 (bf16), BN folded; table t source {0,1,1,2,0,2} ----
    {
        const int src[6] = { 0, 1, 1, 2, 0, 2 };
        for (int t = 0; t < 6; ++t)
            embw_bf16_kernel<<<3125, 256, 0, stream>>>(acc[src[t]], stats + src[t] * 128,
                                                       bw0 + (size_t)t * 4096, tbl[t]);
    }

    // ---- layer 2 pool ----
    hipMemsetAsync(R1, 0, 76800000, stream);
    for (int r = 0; r < 3; ++r)
        l2scat_kernel<<<2048, 256, 0, stream>>>(tbl[2 * r], tbl[2 * r + 1],
                                                row[r], col[r],
                                                ic6[2 * r], ic6[2 * r + 1],
                                                pw1 + (size_t)(2 * r) * 4096,
                                                pw1 + (size_t)(2 * r + 1) * 4096,
                                                acc[REL_EI[r]], acc[REL_EJ[r]]);
    for (int e = 0; e < 3; ++e)
        relu_stats_kernel<<<512, 256, 0, stream>>>(acc[e], stats + (3 + e) * 128);

    // ---- bcast tables embW2 (bf16): only tables {0,1,4,5}, srcs {0,1,0,2} ----
    embw_bf16_kernel<<<3125, 256, 0, stream>>>(acc[0], stats + (3 + 0) * 128,
                                               bw1 + (size_t)0 * 4096, tbl[0]);
    embw_bf16_kernel<<<3125, 256, 0, stream>>>(acc[1], stats + (3 + 1) * 128,
                                               bw1 + (size_t)1 * 4096, tbl[1]);
    embw_bf16_kernel<<<3125, 256, 0, stream>>>(acc[0], stats + (3 + 0) * 128,
                                               bw1 + (size_t)4 * 4096, tbl[2]);
    embw_bf16_kernel<<<3125, 256, 0, stream>>>(acc[2], stats + (3 + 2) * 128,
                                               bw1 + (size_t)5 * 4096, tbl[3]);

    // ---- final pool: entity 0, rows of rel0 (pw2 tbl 0) and rel2 (pw2 tbl 4) ----
    hipMemsetAsync(out, 0, (size_t)out_size * 4, stream);
    fscat_kernel<<<1024, 256, 0, stream>>>(tbl[0], tbl[1], row[0], col[0],
                                           ic6[0], pw2, out);
    fscat_kernel<<<1024, 256, 0, stream>>>(tbl[2], tbl[3], row[2], col[2],
                                           ic6[4], pw2 + 4096, out);
}

// Round 9
// 2751.436 us; speedup vs baseline: 1.3866x; 1.3866x over previous
//
#include <hip/hip_runtime.h>

// ---------------------------------------------------------------------------
// AlternatingHGN: RELS={(0,1),(1,2),(0,2)}, NE=100000 each, NNZ=500000,
// C_IN=16, EMB=WIDTH=64, OUT=16.
//
// Design (ws 158.4 MB):
//  - counts/inv-counts per role computed once (indices reused every layer)
//  - pool = scatter-matmul: per nnz, (v * 1/cnt) @ pw scattered straight into
//    per-entity pre-activation acc (fp32 atomics)
//  - relu + BN stats in place on acc; BN folded into the bcast weight when
//    building gather tables embW (bf16)
//  - final pool scatters straight into d_out
//  R6: latency fixes — 2-nnz ILP everywhere, fscat k-split across subgroups
//      (16-step chains + shfl_xor reduce), bf16-packed l2 weights (16KB LDS),
//      embw 2-row ILP, bigger grids.
// ---------------------------------------------------------------------------

#define NE_  100000
#define NNZ_ 500000

__device__ __forceinline__ ushort f2bf(float x) {
    uint32_t u = __float_as_uint(x);
    u += 0x7fffu + ((u >> 16) & 1u);
    return (ushort)(u >> 16);
}
__device__ __forceinline__ float bf2f(ushort h) {
    return __uint_as_float(((uint32_t)h) << 16);
}

// ------------------------------ kernels ------------------------------------

__global__ __launch_bounds__(256)
void count_kernel(const int* __restrict__ row, const int* __restrict__ col,
                  int* __restrict__ cntR, int* __restrict__ cntC)
{
    int g = blockIdx.x * 256 + threadIdx.x;
    if (g < NNZ_) {
        atomicAdd(&cntR[row[g]], 1);
        atomicAdd(&cntC[col[g]], 1);
    }
}

__global__ __launch_bounds__(256)
void inv_kernel(const int* __restrict__ cnt, float* __restrict__ icnt, int n)
{
    int g = blockIdx.x * 256 + threadIdx.x;
    if (g < n) icnt[g] = 1.f / fmaxf((float)cnt[g], 1.f);
}

// L1 scatter-matmul, 2-nnz ILP: lanes 0-15 carry vals of nnz n0, lanes 32-47
// carry vals of nnz n1. Per c: 2 shfl + shared LDS read + 4 FMA.
__global__ __launch_bounds__(256)
void l1scat_kernel(const float* __restrict__ vals,
                   const int* __restrict__ row, const int* __restrict__ col,
                   const float* __restrict__ icR_t, const float* __restrict__ icC_t,
                   const float* __restrict__ pwR, const float* __restrict__ pwC,
                   float* __restrict__ accR, float* __restrict__ accC)
{
    __shared__ float2 w[16 * 64];          // 8 KB: (pwR, pwC) interleaved
    int t = threadIdx.x;
    for (int i = t; i < 1024; i += 256) w[i] = make_float2(pwR[i], pwC[i]);
    __syncthreads();
    int lane = t & 63, sub = t >> 6;
    for (int n0 = (blockIdx.x * 4 + sub) * 2; n0 < NNZ_; n0 += gridDim.x * 8) {
        int n1 = n0 + 1;                   // NNZ even, n0 even -> n1 valid
        int i0 = row[n0], j0 = col[n0], i1 = row[n1], j1 = col[n1];
        float icR0 = icR_t[i0], icC0 = icC_t[j0];
        float icR1 = icR_t[i1], icC1 = icC_t[j1];
        float vl = 0.f;
        if (lane < 16)                    vl = vals[(size_t)n0 * 16 + lane];
        else if (lane >= 32 && lane < 48) vl = vals[(size_t)n1 * 16 + (lane - 32)];
        float oR0 = 0.f, oC0 = 0.f, oR1 = 0.f, oC1 = 0.f;
#pragma unroll
        for (int c = 0; c < 16; ++c) {
            float vc0 = __shfl(vl, c);
            float vc1 = __shfl(vl, 32 + c);
            float2 ww = w[c * 64 + lane];
            oR0 += vc0 * ww.x; oC0 += vc0 * ww.y;
            oR1 += vc1 * ww.x; oC1 += vc1 * ww.y;
        }
        atomicAdd(&accR[(size_t)i0 * 64 + lane], oR0 * icR0);
        atomicAdd(&accC[(size_t)j0 * 64 + lane], oC0 * icC0);
        atomicAdd(&accR[(size_t)i1 * 64 + lane], oR1 * icR1);
        atomicAdd(&accC[(size_t)j1 * 64 + lane], oC1 * icC1);
    }
}

// in-place relu + per-feature BN stats (sum, sumsq) over one entity table
__global__ __launch_bounds__(256)
void relu_stats_kernel(float* __restrict__ acc, float* __restrict__ stats)
{
    __shared__ float red[2][256];
    int t = threadIdx.x, f = t & 63, sub = t >> 6;
    float s = 0.f, s2 = 0.f;
    for (int r = blockIdx.x * 4 + sub; r < NE_; r += gridDim.x * 4) {
        float x = acc[(size_t)r * 64 + f];
        x = fmaxf(x, 0.f);
        acc[(size_t)r * 64 + f] = x;
        s += x; s2 += x * x;
    }
    red[0][t] = s; red[1][t] = s2;
    __syncthreads();
    if (sub == 0) {
        float rs = red[0][f] + red[0][64 + f] + red[0][128 + f] + red[0][192 + f];
        float rq = red[1][f] + red[1][64 + f] + red[1][128 + f] + red[1][192 + f];
        atomicAdd(&stats[f], rs);
        atomicAdd(&stats[64 + f], rq);
    }
}

// embW = bn(emb) @ bw with BN folded; bf16 output. 2-row ILP per thread.
__global__ __launch_bounds__(256)
void embw_bf16_kernel(const float* __restrict__ emb, const float* __restrict__ stats,
                      const float* __restrict__ bw, ushort* __restrict__ out)
{
    __shared__ float w[64 * 64];
    __shared__ float bias[64], invs[64], mu[64];
    __shared__ float rows[8][64];
    int t = threadIdx.x;
    if (t < 64) {
        float s = stats[t], q = stats[64 + t];
        float m = s * (1.f / (float)NE_);
        float v = q * (1.f / (float)NE_) - m * m;
        mu[t] = m;
        invs[t] = rsqrtf(v + 1e-5f);
    }
    __syncthreads();
    for (int i = t; i < 64 * 64; i += 256) w[i] = bw[i] * invs[i >> 6];
    __syncthreads();
    if (t < 64) {
        float b = 0.f;
        for (int k = 0; k < 64; ++k) b -= mu[k] * w[k * 64 + t];
        bias[t] = b;
    }
    int f = t & 63, sub = t >> 6;
    size_t base = (size_t)blockIdx.x * 32;   // 3125 blocks x 32 rows = 100000
    for (int it = 0; it < 32; it += 8) {
        __syncthreads();
        for (int i = t; i < 512; i += 256) {
            size_t rr = base + it + (i >> 6);
            rows[i >> 6][i & 63] = emb[rr * 64 + (i & 63)];
        }
        __syncthreads();
        size_t rr0 = base + it + sub;
        size_t rr1 = rr0 + 4;
        float a0 = bias[f], a1 = bias[f];
#pragma unroll
        for (int k = 0; k < 64; ++k) {
            float wkf = w[k * 64 + f];
            a0 += rows[sub][k] * wkf;
            a1 += rows[sub + 4][k] * wkf;
        }
        out[rr0 * 64 + f] = f2bf(a0);
        out[rr1 * 64 + f] = f2bf(a1);
    }
}

// L2 scatter-matmul, 2-nnz ILP, bf16-packed weights (16 KB LDS).
__global__ __launch_bounds__(256)
void l2scat_kernel(const ushort* __restrict__ ea, const ushort* __restrict__ eb,
                   const int* __restrict__ row, const int* __restrict__ col,
                   const float* __restrict__ icR_t, const float* __restrict__ icC_t,
                   const float* __restrict__ pwR, const float* __restrict__ pwC,
                   float* __restrict__ accR, float* __restrict__ accC)
{
    __shared__ ushort2 w[64 * 64];         // 16 KB: (bf16 wR, bf16 wC)
    int t = threadIdx.x;
    for (int i = t; i < 4096; i += 256)
        w[i] = make_ushort2(f2bf(pwR[i]), f2bf(pwC[i]));
    __syncthreads();
    int lane = t & 63, sub = t >> 6;
    for (int n0 = (blockIdx.x * 4 + sub) * 2; n0 < NNZ_; n0 += gridDim.x * 8) {
        int n1 = n0 + 1;
        int i0 = row[n0], j0 = col[n0], i1 = row[n1], j1 = col[n1];
        float icR0 = icR_t[i0], icC0 = icC_t[j0];
        float icR1 = icR_t[i1], icC1 = icC_t[j1];
        float a0 = bf2f(ea[(size_t)i0 * 64 + lane]);
        float b0 = bf2f(eb[(size_t)j0 * 64 + lane]);
        float a1 = bf2f(ea[(size_t)i1 * 64 + lane]);
        float b1 = bf2f(eb[(size_t)j1 * 64 + lane]);
        float v0 = fmaxf(a0 + b0, 0.f);
        float v1 = fmaxf(a1 + b1, 0.f);
        float oR0 = 0.f, oC0 = 0.f, oR1 = 0.f, oC1 = 0.f;
#pragma unroll
        for (int k = 0; k < 64; ++k) {
            float vk0 = __shfl(v0, k);
            float vk1 = __shfl(v1, k);
            ushort2 wp = w[k * 64 + lane];
            float wR = bf2f(wp.x), wC = bf2f(wp.y);
            oR0 += vk0 * wR; oC0 += vk0 * wC;
            oR1 += vk1 * wR; oC1 += vk1 * wC;
        }
        atomicAdd(&accR[(size_t)i0 * 64 + lane], oR0 * icR0);
        atomicAdd(&accC[(size_t)j0 * 64 + lane], oC0 * icC0);
        atomicAdd(&accR[(size_t)i1 * 64 + lane], oR1 * icR1);
        atomicAdd(&accC[(size_t)j1 * 64 + lane], oC1 * icC1);
    }
}

// final pool, both relations in one launch. Per wave: 2 nnz; k-space split
// across the 4 sub-groups (16-step chains), shfl_xor cross-group reduce.
__global__ __launch_bounds__(256)
void fscat_kernel(const ushort* __restrict__ eaA, const ushort* __restrict__ ebA,
                  const int* __restrict__ rowA, const int* __restrict__ colA,
                  const float* __restrict__ icA,
                  const ushort* __restrict__ eaB, const ushort* __restrict__ ebB,
                  const int* __restrict__ rowB, const int* __restrict__ colB,
                  const float* __restrict__ icB,
                  const float* __restrict__ pwA, const float* __restrict__ pwB,
                  float* __restrict__ out)
{
    __shared__ float w[64 * 17];           // padded: group-split reads <=2-way
    int t = threadIdx.x;
    int halfGrid = gridDim.x >> 1;
    bool second = (blockIdx.x >= halfGrid);
    const ushort* ea = second ? eaB : eaA;
    const ushort* eb = second ? ebB : ebA;
    const int* row = second ? rowB : rowA;
    const int* col = second ? colB : colA;
    const float* ic = second ? icB : icA;
    const float* pw = second ? pwB : pwA;
    int blk = second ? (blockIdx.x - halfGrid) : blockIdx.x;

    for (int i = t; i < 1024; i += 256) w[(i >> 4) * 17 + (i & 15)] = pw[i];
    __syncthreads();
    int lane = t & 63, sub = t >> 6;
    int g = lane >> 4, o = lane & 15;      // group g handles k in [16g,16g+16)
    for (int n0 = (blk * 4 + sub) * 2; n0 < NNZ_; n0 += halfGrid * 8) {
        int n1 = n0 + 1;
        int i0 = row[n0], j0 = col[n0], i1 = row[n1], j1 = col[n1];
        float ic0 = ic[i0], ic1 = ic[i1];
        float a0 = bf2f(ea[(size_t)i0 * 64 + lane]);
        float b0 = bf2f(eb[(size_t)j0 * 64 + lane]);
        float a1 = bf2f(ea[(size_t)i1 * 64 + lane]);
        float b1 = bf2f(eb[(size_t)j1 * 64 + lane]);
        float v0 = fmaxf(a0 + b0, 0.f);
        float v1 = fmaxf(a1 + b1, 0.f);
        float o0 = 0.f, o1 = 0.f;
#pragma unroll
        for (int c = 0; c < 16; ++c) {
            int k = g * 16 + c;
            float vk0 = __shfl(v0, k);
            float vk1 = __shfl(v1, k);
            float wv = w[k * 17 + o];
            o0 += vk0 * wv;
            o1 += vk1 * wv;
        }
        // reduce partial sums across the 4 k-groups
        o0 += __shfl_xor(o0, 16); o0 += __shfl_xor(o0, 32);
        o1 += __shfl_xor(o1, 16); o1 += __shfl_xor(o1, 32);
        if (lane < 16) {
            atomicAdd(&out[(size_t)i0 * 16 + o], o0 * ic0);
            atomicAdd(&out[(size_t)i1 * 16 + o], o1 * ic1);
        }
    }
}

// ------------------------------ launch -------------------------------------

extern "C" void kernel_launch(void* const* d_in, const int* in_sizes, int n_in,
                              void* d_out, int out_size, void* d_ws, size_t ws_size,
                              hipStream_t stream)
{
    const float* vals[3] = { (const float*)d_in[0], (const float*)d_in[3], (const float*)d_in[6] };
    const int*   row[3]  = { (const int*)d_in[1], (const int*)d_in[4], (const int*)d_in[7] };
    const int*   col[3]  = { (const int*)d_in[2], (const int*)d_in[5], (const int*)d_in[8] };
    const float* pw0 = (const float*)d_in[9];
    const float* pw1 = (const float*)d_in[10];
    const float* pw2 = (const float*)d_in[11];
    const float* bw0 = (const float*)d_in[12];
    const float* bw1 = (const float*)d_in[13];
    float* out = (float*)d_out;

    // ---- workspace layout (158.4 MB total) ----
    const size_t OFF_CNT   = 0;                    // 6 * 100000 int  = 2.4 MB
    const size_t OFF_ICNT  = 2400000;              // 6 * 100000 f32  = 2.4 MB
    const size_t OFF_STATS = 4800000;              // 6 * 128 f32
    const size_t OFF_R1    = 4804096;              // 3 * 100000*64 f32 = 76.8 MB
    const size_t OFF_R2    = 81604096;             // 6 * 100000*64 bf16 = 76.8 MB
    const size_t WS_NEED   = 158404096;

    if (ws_size < WS_NEED) {
        hipMemsetAsync(d_out, 0, (size_t)out_size * 4, stream);  // clean fail
        return;
    }

    char* ws = (char*)d_ws;
    int*    cnt   = (int*)(ws + OFF_CNT);
    float*  icnt  = (float*)(ws + OFF_ICNT);
    float*  stats = (float*)(ws + OFF_STATS);
    float*  R1    = (float*)(ws + OFF_R1);
    ushort* R2    = (ushort*)(ws + OFF_R2);

    int* cnt6[6];  float* ic6[6];
    for (int k = 0; k < 6; ++k) { cnt6[k] = cnt + (size_t)k * NE_; ic6[k] = icnt + (size_t)k * NE_; }
    float* acc[3];
    for (int e = 0; e < 3; ++e) acc[e] = R1 + (size_t)e * NE_ * 64;
    ushort* tbl[6];
    for (int k = 0; k < 6; ++k) tbl[k] = R2 + (size_t)k * NE_ * 64;

    const int REL_EI[3] = { 0, 1, 0 };
    const int REL_EJ[3] = { 1, 2, 2 };

    // ---- counts (once; indices identical across layers) ----
    hipMemsetAsync(cnt, 0, 2400000, stream);
    hipMemsetAsync(stats, 0, 3072, stream);
    for (int r = 0; r < 3; ++r)
        count_kernel<<<(NNZ_ + 255) / 256, 256, 0, stream>>>(row[r], col[r],
                                                             cnt6[2 * r], cnt6[2 * r + 1]);
    inv_kernel<<<(6 * NE_ + 255) / 256, 256, 0, stream>>>(cnt, icnt, 6 * NE_);

    // ---- layer 1 pool ----
    hipMemsetAsync(R1, 0, 76800000, stream);
    for (int r = 0; r < 3; ++r)
        l1scat_kernel<<<2048, 256, 0, stream>>>(vals[r], row[r], col[r],
                                                ic6[2 * r], ic6[2 * r + 1],
                                                pw0 + (size_t)(2 * r) * 1024,
                                                pw0 + (size_t)(2 * r + 1) * 1024,
                                                acc[REL_EI[r]], acc[REL_EJ[r]]);
    for (int e = 0; e < 3; ++e)
        relu_stats_kernel<<<512, 256, 0, stream>>>(acc[e], stats + e * 128);

    // ---- bcast tables embW1 (bf16), BN folded; table t source {0,1,1,2,0,2} ----
    {
        const int src[6] = { 0, 1, 1, 2, 0, 2 };
        for (int t = 0; t < 6; ++t)
            embw_bf16_kernel<<<3125, 256, 0, stream>>>(acc[src[t]], stats + src[t] * 128,
                                                       bw0 + (size_t)t * 4096, tbl[t]);
    }

    // ---- layer 2 pool ----
    hipMemsetAsync(R1, 0, 76800000, stream);
    for (int r = 0; r < 3; ++r)
        l2scat_kernel<<<2048, 256, 0, stream>>>(tbl[2 * r], tbl[2 * r + 1],
                                                row[r], col[r],
                                                ic6[2 * r], ic6[2 * r + 1],
                                                pw1 + (size_t)(2 * r) * 4096,
                                                pw1 + (size_t)(2 * r + 1) * 4096,
                                                acc[REL_EI[r]], acc[REL_EJ[r]]);
    for (int e = 0; e < 3; ++e)
        relu_stats_kernel<<<512, 256, 0, stream>>>(acc[e], stats + (3 + e) * 128);

    // ---- bcast tables embW2 (bf16): only tables {0,1,4,5}, srcs {0,1,0,2} ----
    embw_bf16_kernel<<<3125, 256, 0, stream>>>(acc[0], stats + (3 + 0) * 128,
                                               bw1 + (size_t)0 * 4096, tbl[0]);
    embw_bf16_kernel<<<3125, 256, 0, stream>>>(acc[1], stats + (3 + 1) * 128,
                                               bw1 + (size_t)1 * 4096, tbl[1]);
    embw_bf16_kernel<<<3125, 256, 0, stream>>>(acc[0], stats + (3 + 0) * 128,
                                               bw1 + (size_t)4 * 4096, tbl[2]);
    embw_bf16_kernel<<<3125, 256, 0, stream>>>(acc[2], stats + (3 + 2) * 128,
                                               bw1 + (size_t)5 * 4096, tbl[3]);

    // ---- final pool: entity 0, rows of rel0 (pw2 tbl 0) and rel2 (pw2 tbl 4) ----
    hipMemsetAsync(out, 0, (size_t)out_size * 4, stream);
    fscat_kernel<<<2048, 256, 0, stream>>>(tbl[0], tbl[1], row[0], col[0], ic6[0],
                                           tbl[2], tbl[3], row[2], col[2], ic6[4],
                                           pw2, pw2 + 4096, out);
}